// Round 20
// baseline (119.930 us; speedup 1.0000x reference)
//
#include <hip/hip_runtime.h>
#include <math.h>

#define TPB 256
#define ATPB 512
#define QSCALE 0.1803368801111204f   // 0.125 * log2(e): folds 1/sqrt(dk) and exp->exp2

typedef __attribute__((ext_vector_type(8))) _Float16 f16x8;
typedef __attribute__((ext_vector_type(8))) unsigned short u16x8;
typedef __attribute__((ext_vector_type(4))) float f32x4;
typedef __attribute__((ext_vector_type(16))) float f32x16;
typedef __attribute__((ext_vector_type(4))) unsigned int u32x4;
typedef unsigned short u16;
typedef unsigned int u32;

#define MFMA16F(a, b, c) __builtin_amdgcn_mfma_f32_16x16x32_f16((a), (b), (c), 0, 0, 0)
#define MFMA32F(a, b, c) __builtin_amdgcn_mfma_f32_32x32x16_f16((a), (b), (c), 0, 0, 0)

__device__ __forceinline__ u16 f2h(float f) {
    return __builtin_bit_cast(u16, (_Float16)f);
}
__device__ __forceinline__ u16 f2bf(float f) {           // RNE (mask table only)
    unsigned int u = __float_as_uint(f);
    return (u16)((u + 0x7FFFu + ((u >> 16) & 1u)) >> 16);
}

// ---------------------------------------------------------------------------
// Fused prep: [0,2048) X fp32->fp16 | [2048,2560) weights | [2560,2641) mask.
// ---------------------------------------------------------------------------
__global__ __launch_bounds__(TPB)
void prep(const float* __restrict__ x,
          const float* __restrict__ w0, const float* __restrict__ w1,
          const float* __restrict__ w2, const float* __restrict__ w3,
          u16* __restrict__ Xf, u16* __restrict__ WS,
          u16* __restrict__ WOh, u16* __restrict__ WOl,
          u32* __restrict__ mws)
{
    const int bid = blockIdx.x;
    const int t = threadIdx.x;

    if (bid < 2048) {                       // ---- X fp32 -> fp16 ----
        size_t i = ((size_t)bid * TPB + t) * 8;
        float4 a = *reinterpret_cast<const float4*>(x + i);
        float4 b = *reinterpret_cast<const float4*>(x + i + 4);
        float v[8] = {a.x, a.y, a.z, a.w, b.x, b.y, b.z, b.w};
        u16x8 hv;
        #pragma unroll
        for (int k = 0; k < 8; ++k) hv[k] = f2h(v[k]);
        *reinterpret_cast<u16x8*>(Xf + i) = hv;
    } else if (bid < 2560) {                // ---- weights ----
        int bb = bid - 2048;
        int y = bb >> 7, xb = bb & 127;
        const float* src = (y == 0) ? w0 : (y == 1) ? w1 : (y == 2) ? w2 : w3;
        float sc = (y == 0) ? QSCALE : 1.0f;
        size_t i = ((size_t)xb * TPB + t) * 8;
        float4 a = *reinterpret_cast<const float4*>(src + i);
        float4 b = *reinterpret_cast<const float4*>(src + i + 4);
        float v[8] = {a.x, a.y, a.z, a.w, b.x, b.y, b.z, b.w};
        if (y < 3) {
            size_t base = (size_t)y * 262144;
            u16x8 hv;
            #pragma unroll
            for (int k = 0; k < 8; ++k) hv[k] = f2h(v[k] * sc);
            *reinterpret_cast<u16x8*>(WS + base + i) = hv;
        } else {
            u16x8 hv, lv;
            #pragma unroll
            for (int k = 0; k < 8; ++k) {
                _Float16 h = (_Float16)v[k];
                hv[k] = __builtin_bit_cast(u16, h);
                lv[k] = f2h(v[k] - (float)h);
            }
            *reinterpret_cast<u16x8*>(WOh + i) = hv;
            *reinterpret_cast<u16x8*>(WOl + i) = lv;
        }
    } else {                                // ---- compact bf16 mask table ----
        int mb = bid - 2560;                // 0..80
        int mq9 = mb / 9, mk9 = mb % 9;
        int w = t >> 6, l = t & 63, lh = l >> 5, l31 = l & 31;
        int q = mq9 * 16 + (w & 1) * 32 + l31;
        int qx = q % 12, qy = (q / 12) % 12;
        u32 words[8];
        #pragma unroll
        for (int jr = 0; jr < 8; ++jr) {
            u16 wb[2];
            #pragma unroll
            for (int e = 0; e < 2; ++e) {
                int r = jr * 2 + e;
                int key = mk9 * 16 + (w >> 1) * 32 + (r & 3) + 8 * (r >> 2) + 4 * lh;
                int kx = key % 12, ky = (key / 12) % 12;
                int dx = qx - kx; dx = dx < 0 ? -dx : dx; dx = dx < 12 - dx ? dx : 12 - dx;
                int dy = qy - ky; dy = dy < 0 ? -dy : dy; dy = dy < 12 - dy ? dy : 12 - dy;
                int d = dx + dy;
                float wgt = (d <= 2) ? 1.0f : __expf(-(float)d);
                wb[e] = f2bf(wgt);
            }
            words[jr] = (u32)wb[0] | ((u32)wb[1] << 16);
        }
        u32* dst = &mws[(size_t)((mb * 4 + w) * 64 + l) * 8];
        #pragma unroll
        for (int jr = 0; jr < 8; ++jr) dst[jr] = words[jr];
    }
}

// ---------------------------------------------------------------------------
// Single-precision fp16 QKV GEMM, 64x128 tiles (1536 blocks = ~6/CU so
// cross-block overlap hides the per-k-step barrier drain — the mechanism
// that worked for gemm_o2 in round 17; barrier-structure attacks did not).
// BK=32 single-buffer 2-barrier body (round-17 proven). LDS 12 KB.
// XCD k owns m-tiles [16k,16k+16) x all 12 n-tiles (X panel 1 MB + W 1.5 MB
// L2-resident per XCD).
// ---------------------------------------------------------------------------
__global__ __launch_bounds__(TPB)
void gemm_qkv(const u16* __restrict__ Xf, const u16* __restrict__ Wc,
              const float* __restrict__ bq, const float* __restrict__ bk,
              const float* __restrict__ bv,
              u16* __restrict__ Qf, u16* __restrict__ Kf, u16* __restrict__ Vt)
{
    __shared__ __align__(16) u16 XS[64][32];
    __shared__ __align__(16) u16 WSs[128][32];

    const int bid = blockIdx.x;                // 1536 blocks
    const int xcd = bid & 7, idx = bid >> 3;   // idx 0..191
    const int m0 = (xcd * 16 + (idx & 15)) * 64;
    const int n0 = (idx >> 4) * 128;           // 0..11 n-tiles

    const int t  = threadIdx.x;
    const int wv = t >> 6, l = t & 63, lr = l & 15, lg = l >> 4;
    const int wm = (wv >> 1) * 32, wn = (wv & 1) * 64;

    // staging: waves 0,1 -> X rows (wv*32..wv*32+32), 2 insts each;
    //          waves 2,3 -> W rows ((wv-2)*64..), 4 insts each
    const u16* gsrc = (wv < 2) ? Xf : Wc;
    const int rbase = (wv < 2) ? m0 : n0;
    const int rgoff = (wv < 2) ? (wv * 32) : ((wv - 2) * 64);
    const int nld   = (wv < 2) ? 2 : 4;
    u16 (*dst)[32] = (wv < 2) ? XS : WSs;
    const int srow  = l >> 2;
    const int scol  = ((l & 3) ^ ((l >> 3) & 3)) * 8;   // inverse-swizzled source
    const int swc   = (lg ^ ((lr >> 1) & 3)) * 8;       // swizzled read col

    f32x4 acc[2][4];
    #pragma unroll
    for (int i = 0; i < 2; ++i)
        #pragma unroll
        for (int j = 0; j < 4; ++j) acc[i][j] = f32x4{};

    for (int k0 = 0; k0 < 512; k0 += 32) {
        __syncthreads();
        for (int j = 0; j < nld; ++j) {
            int row0 = rgoff + j * 16;
            const u16* g = gsrc + (size_t)(rbase + row0 + srow) * 512 + k0 + scol;
            __builtin_amdgcn_global_load_lds(
                (const __attribute__((address_space(1))) void*)g,
                (__attribute__((address_space(3))) void*)&dst[row0][0],
                16, 0, 0);
        }
        __syncthreads();

        f16x8 af[2], bfr[4];
        #pragma unroll
        for (int mi = 0; mi < 2; ++mi)
            af[mi] = *reinterpret_cast<const f16x8*>(&XS[wm + mi*16 + lr][swc]);
        #pragma unroll
        for (int ni = 0; ni < 4; ++ni)
            bfr[ni] = *reinterpret_cast<const f16x8*>(&WSs[wn + ni*16 + lr][swc]);
        #pragma unroll
        for (int mi = 0; mi < 2; ++mi)
            #pragma unroll
            for (int ni = 0; ni < 4; ++ni)
                acc[mi][ni] = MFMA16F(af[mi], bfr[ni], acc[mi][ni]);
    }

    const int proj = n0 >> 9;
    const float* bias = (proj == 0) ? bq : (proj == 1) ? bk : bv;
    const float bsc = (proj == 0) ? QSCALE : 1.0f;
    #pragma unroll
    for (int ni = 0; ni < 4; ++ni) {
        int gn = n0 + wn + ni*16 + lr;
        int nn = gn & 511;
        float bb = bias[nn] * bsc;
        #pragma unroll
        for (int mi = 0; mi < 2; ++mi) {
            #pragma unroll
            for (int j = 0; j < 4; ++j) {
                int gm = m0 + wm + mi*16 + lg*4 + j;
                float v = acc[mi][ni][j] + bb;
                int b = gm >> 11, tt = gm & 2047, hh = nn >> 6, d = nn & 63;
                if (proj == 0) {
                    Qf[(((size_t)(b*8 + hh) * 2048) + tt) * 64 + d] = f2h(v);
                } else if (proj == 1) {
                    Kf[(((size_t)(b*8 + hh) * 2048) + tt) * 64 + d] = f2h(v);
                } else {
                    int ttp = (tt & ~12) | ((tt & 4) << 1) | ((tt & 8) >> 1);
                    Vt[(((size_t)(b*8 + hh) * 64) + d) * 2048 + ttp] = f2h(v);
                }
            }
        }
    }
}

// ---------------------------------------------------------------------------
// 2-term out-projection GEMM, 64x128 tiles, XCD-remapped (round-17, frozen).
// ---------------------------------------------------------------------------
__global__ __launch_bounds__(TPB)
void gemm_o2(const u16* __restrict__ A_g, const u16* __restrict__ Bh_g,
             const u16* __restrict__ Bl_g,
             const float* __restrict__ b0, float* __restrict__ outf)
{
    __shared__ __align__(16) u16 AS[64][32];
    __shared__ __align__(16) u16 BhS[128][32];
    __shared__ __align__(16) u16 BlS[128][32];

    const int bid = blockIdx.x;            // 512 blocks
    const int xcd = bid & 7, idx = bid >> 3;   // idx 0..63
    const int m0 = (xcd * 16 + (idx & 15)) * 64;
    const int n0 = (idx >> 4) * 128;           // 0..3

    const int t  = threadIdx.x;
    const int wv = t >> 6, l = t & 63, lr = l & 15, lg = l >> 4;
    const int wm = (wv >> 1) * 32, wn = (wv & 1) * 64;

    const u16* gsrc = (wv < 2) ? A_g : (wv == 2) ? Bh_g : Bl_g;
    const int rbase = (wv < 2) ? m0 : n0;
    const int rgoff = (wv == 1) ? 32 : 0;
    const int nld   = (wv < 2) ? 2 : 8;
    u16 (*dst)[32] = (wv < 2) ? AS : (wv == 2) ? BhS : BlS;
    const int srow  = l >> 2;
    const int scol  = ((l & 3) ^ ((l >> 3) & 3)) * 8;
    const int swc   = (lg ^ ((lr >> 1) & 3)) * 8;

    f32x4 acc[2][4];
    #pragma unroll
    for (int i = 0; i < 2; ++i)
        #pragma unroll
        for (int j = 0; j < 4; ++j) acc[i][j] = f32x4{};

    for (int k0 = 0; k0 < 512; k0 += 32) {
        __syncthreads();
        for (int j = 0; j < nld; ++j) {
            int row0 = rgoff + j * 16;
            const u16* g = gsrc + (size_t)(rbase + row0 + srow) * 512 + k0 + scol;
            __builtin_amdgcn_global_load_lds(
                (const __attribute__((address_space(1))) void*)g,
                (__attribute__((address_space(3))) void*)&dst[row0][0],
                16, 0, 0);
        }
        __syncthreads();

        f16x8 af[2], bfh[4], bfl[4];
        #pragma unroll
        for (int mi = 0; mi < 2; ++mi)
            af[mi] = *reinterpret_cast<const f16x8*>(&AS[wm + mi*16 + lr][swc]);
        #pragma unroll
        for (int ni = 0; ni < 4; ++ni) {
            bfh[ni] = *reinterpret_cast<const f16x8*>(&BhS[wn + ni*16 + lr][swc]);
            bfl[ni] = *reinterpret_cast<const f16x8*>(&BlS[wn + ni*16 + lr][swc]);
        }
        #pragma unroll
        for (int mi = 0; mi < 2; ++mi)
            #pragma unroll
            for (int ni = 0; ni < 4; ++ni) {
                acc[mi][ni] = MFMA16F(af[mi], bfh[ni], acc[mi][ni]);
                acc[mi][ni] = MFMA16F(af[mi], bfl[ni], acc[mi][ni]);
            }
    }

    #pragma unroll
    for (int ni = 0; ni < 4; ++ni) {
        int gn = n0 + wn + ni*16 + lr;
        float bb = b0[gn];
        #pragma unroll
        for (int mi = 0; mi < 2; ++mi) {
            #pragma unroll
            for (int j = 0; j < 4; ++j) {
                int gm = m0 + wm + mi*16 + lg*4 + j;
                outf[(size_t)gm * 512 + gn] = acc[mi][ni][j] + bb;
            }
        }
    }
}

// ---------------------------------------------------------------------------
// Flash attention: round-17 exact (byte-identical; 53.5 us / 9.77e-4 proven).
// ---------------------------------------------------------------------------
__device__ __forceinline__ int lidx(int row, int col) {    // col multiple of 8
    return row * 64 + (col ^ ((row & 7) << 3));
}

__global__ __launch_bounds__(ATPB)
void attn32(const u16* __restrict__ Qf_g, const u16* __restrict__ K_g,
            const u16* __restrict__ Vt_g, const u32* __restrict__ mws,
            u16* __restrict__ AO)
{
    __shared__ __align__(16) u16 SMEM[16384];   // KS dbuf | VS dbuf; reused as OSC
    __shared__ float SC[8][64];
    __shared__ float ILS[128];
    u16* KS0 = SMEM;            // [2][4096]
    u16* VS0 = SMEM + 8192;     // [2][4096]

    const int t = threadIdx.x;
    int id  = blockIdx.x;                 // 512 blocks: 8 XCD x 4 bh x 16 q-tiles
    int xcd = id & 7, seq = id >> 3;
    int bh  = xcd * 4 + (seq >> 4);
    int qt  = seq & 15;
    const int q0 = qt * 128;
    const int b = bh >> 3, h = bh & 7;
    const int w = t >> 6, l = t & 63, lh = l >> 5, l31 = l & 31;
    const int qg = w >> 1, kh = w & 1;
    const int mq9 = ((q0 + qg * 32) % 144) >> 4;

    // Q B-fragments (single fp16): col q = q0 + qg*32 + l31, k = ks*16 + lh*8 + j
    const u16* Qfb = Qf_g + ((size_t)bh * 2048 + q0 + qg * 32 + l31) * 64;
    f16x8 qf[4];
    #pragma unroll
    for (int ks = 0; ks < 4; ++ks)
        qf[ks] = *reinterpret_cast<const f16x8*>(&Qfb[ks * 16 + lh * 8]);

    const u16* Kb = K_g  + (size_t)bh * 2048 * 64;
    const u16* Vb = Vt_g + (size_t)bh * 64 * 2048;
    const int sr = t >> 3, sc8 = (t & 7) * 8;

    // prologue: tile0 -> buf0, prefetch tile1 into regs
    u16x8 kst = *reinterpret_cast<const u16x8*>(&Kb[(size_t)sr * 64 + sc8]);
    u16x8 vst = *reinterpret_cast<const u16x8*>(&Vb[(size_t)sr * 2048 + sc8]);
    *reinterpret_cast<u16x8*>(&KS0[lidx(sr, sc8)]) = kst;
    *reinterpret_cast<u16x8*>(&VS0[lidx(sr, sc8)]) = vst;
    kst = *reinterpret_cast<const u16x8*>(&Kb[(size_t)(64 + sr) * 64 + sc8]);
    vst = *reinterpret_cast<const u16x8*>(&Vb[(size_t)sr * 2048 + 64 + sc8]);
    __syncthreads();

    f32x16 o0 = {}, o1 = {};
    float lrow = 0.f;

    for (int kt = 0; kt < 32; ++kt) {
        const int cur = kt & 1;

        // bf16-packed mask words (L2-resident; consumed after QK^T)
        int mk9 = (4 * kt) % 9;
        const u32* mp = &mws[(size_t)((((mq9 * 9 + mk9) * 4 + (kh << 1)) * 64 + l)) * 8];
        u32x4 mwa = *reinterpret_cast<const u32x4*>(mp);
        u32x4 mwb = *reinterpret_cast<const u32x4*>(mp + 4);

        // S^T = K Q^T (single chain, 4 MFMA32)
        f32x16 st = {};
        __builtin_amdgcn_s_setprio(1);
        #pragma unroll
        for (int ks = 0; ks < 4; ++ks) {
            f16x8 kf = *reinterpret_cast<const f16x8*>(&KS0[cur * 4096 + lidx(kh * 32 + l31, ks * 16 + lh * 8)]);
            st = MFMA32F(kf, qf[ks], st);
        }
        __builtin_amdgcn_s_setprio(0);

        // stage next tile into the other buffer; prefetch tile kt+2
        if (kt < 31) {
            *reinterpret_cast<u16x8*>(&KS0[(cur ^ 1) * 4096 + lidx(sr, sc8)]) = kst;
            *reinterpret_cast<u16x8*>(&VS0[(cur ^ 1) * 4096 + lidx(sr, sc8)]) = vst;
        }
        if (kt < 30) {
            int k0n = (kt + 2) * 64;
            kst = *reinterpret_cast<const u16x8*>(&Kb[(size_t)(k0n + sr) * 64 + sc8]);
            vst = *reinterpret_cast<const u16x8*>(&Vb[(size_t)sr * 2048 + k0n + sc8]);
        }

        // p = exp2(s * w); raw v_exp_f32 (guard-free; args well in range)
        float p[16];
        #pragma unroll
        for (int r = 0; r < 16; ++r) {
            u32 word = (r < 8) ? mwa[r >> 1] : mwb[(r >> 1) - 4];
            u32 bits = (r & 1) ? (word & 0xFFFF0000u) : (word << 16);
            float wgt = __uint_as_float(bits);
            p[r] = __builtin_amdgcn_exp2f(st[r] * wgt);
            lrow += p[r];
        }

        // PV: quantize P to fp16 (RNE scalar) -> direct A-frag
        __builtin_amdgcn_s_setprio(1);
        #pragma unroll
        for (int ks = 0; ks < 2; ++ks) {
            const int base = ks * 8;
            f16x8 pa;
            #pragma unroll
            for (int j = 0; j < 8; ++j) pa[j] = (_Float16)p[base + j];
            f16x8 v0 = *reinterpret_cast<const f16x8*>(&VS0[cur * 4096 + lidx(l31,      kh * 32 + ks * 16 + lh * 8)]);
            f16x8 v1 = *reinterpret_cast<const f16x8*>(&VS0[cur * 4096 + lidx(32 + l31, kh * 32 + ks * 16 + lh * 8)]);
            o0 = MFMA32F(pa, v0, o0);
            o1 = MFMA32F(pa, v1, o1);
        }
        __builtin_amdgcn_s_setprio(0);
        __syncthreads();
    }

    // ---- merge: lrow across (lane-half, key-half); O across key-halves ----
    SC[w][l] = lrow;
    __syncthreads();
    float* OSC = (float*)SMEM;                    // [128 q][64 d] = 32 KB
    if (kh == 1) {
        #pragma unroll
        for (int r = 0; r < 16; ++r) {
            int q = qg * 32 + (r & 3) + 8 * (r >> 2) + 4 * lh;
            OSC[q * 64 + l31]      = o0[r];
            OSC[q * 64 + 32 + l31] = o1[r];
        }
    } else if (l < 32) {
        float s = SC[qg*2][l31] + SC[qg*2][l31 + 32] + SC[qg*2 + 1][l31] + SC[qg*2 + 1][l31 + 32];
        ILS[qg * 32 + l31] = 1.0f / s;
    }
    __syncthreads();
    if (kh == 0) {
        #pragma unroll
        for (int r = 0; r < 16; ++r) {
            int q = qg * 32 + (r & 3) + 8 * (r >> 2) + 4 * lh;
            float il = ILS[q];
            float v0 = (o0[r] + OSC[q * 64 + l31]) * il;
            float v1 = (o1[r] + OSC[q * 64 + 32 + l31]) * il;
            size_t row = (size_t)b * 2048 + q0 + q;
            size_t off0 = row * 512 + h * 64 + l31;
            AO[off0]      = f2h(v0);
            AO[off0 + 32] = f2h(v1);
        }
    }
}

// ---------------------------------------------------------------------------
extern "C" void kernel_launch(void* const* d_in, const int* in_sizes, int n_in,
                              void* d_out, int out_size, void* d_ws, size_t ws_size,
                              hipStream_t stream)
{
    (void)in_sizes; (void)n_in; (void)out_size; (void)ws_size;
    const float* x  = (const float*)d_in[0];
    const float* Wq = (const float*)d_in[1];
    const float* bq = (const float*)d_in[2];
    const float* Wk = (const float*)d_in[3];
    const float* bk = (const float*)d_in[4];
    const float* Wv = (const float*)d_in[5];
    const float* bv = (const float*)d_in[6];
    const float* Wo = (const float*)d_in[7];
    const float* bo = (const float*)d_in[8];
    float* out = (float*)d_out;

    // workspace (~35 MB):
    u16* Xf  = (u16*)d_ws;                // 8 MB (reused as AO after QKV)
    u16* WS  = Xf + 4194304;              // 1.5 MB ([1536][512] f16, Wq*QSCALE)
    u16* WOh = WS + 786432;               // 0.5 MB
    u16* WOl = WOh + 262144;              // 0.5 MB
    u16* Qf  = WOl + 262144;              // 8 MB
    u16* Kf  = Qf + 4194304;              // 8 MB
    u16* Vt  = Kf + 4194304;              // 8 MB (key-permuted transposed)
    u32* MW  = (u32*)(Vt + 4194304);      // 648 KB (bf16-packed compact mask)
    u16* AO  = Xf;

    // fused prep: X cvt (2048) + weights (512) + mask table (81)
    prep<<<2641, TPB, 0, stream>>>(x, Wq, Wk, Wv, Wo, Xf, WS, WOh, WOl, MW);

    // fused QKV projection: 1536 blocks (64x128 tiles), XCD-remapped
    gemm_qkv<<<1536, TPB, 0, stream>>>(Xf, WS, bq, bk, bv, Qf, Kf, Vt);

    // 8-wave attention: 512 blocks x 512 threads
    attn32<<<512, ATPB, 0, stream>>>(Qf, Kf, Vt, MW, AO);

    // output projection (2-term), 64x128 tiles, XCD-remapped
    gemm_o2<<<512, TPB, 0, stream>>>(AO, WOh, WOl, bo, out);
}

// Round 21
// 109.140 us; speedup vs baseline: 1.0989x; 1.0989x over previous
//
#include <hip/hip_runtime.h>
#include <math.h>

#define TPB 256
#define ATPB 512
#define QSCALE 0.1803368801111204f   // 0.125 * log2(e): folds 1/sqrt(dk) and exp->exp2

typedef __attribute__((ext_vector_type(8))) _Float16 f16x8;
typedef __attribute__((ext_vector_type(8))) unsigned short u16x8;
typedef __attribute__((ext_vector_type(4))) float f32x4;
typedef __attribute__((ext_vector_type(16))) float f32x16;
typedef __attribute__((ext_vector_type(4))) unsigned int u32x4;
typedef unsigned short u16;
typedef unsigned int u32;

#define MFMA16F(a, b, c) __builtin_amdgcn_mfma_f32_16x16x32_f16((a), (b), (c), 0, 0, 0)
#define MFMA32F(a, b, c) __builtin_amdgcn_mfma_f32_32x32x16_f16((a), (b), (c), 0, 0, 0)

__device__ __forceinline__ u16 f2h(float f) {
    return __builtin_bit_cast(u16, (_Float16)f);
}
__device__ __forceinline__ u16 f2bf(float f) {           // RNE (mask table only)
    unsigned int u = __float_as_uint(f);
    return (u16)((u + 0x7FFFu + ((u >> 16) & 1u)) >> 16);
}

// ---------------------------------------------------------------------------
// Fused prep: [0,2048) X fp32->fp16 | [2048,2560) weights | [2560,2641) mask.
// ---------------------------------------------------------------------------
__global__ __launch_bounds__(TPB)
void prep(const float* __restrict__ x,
          const float* __restrict__ w0, const float* __restrict__ w1,
          const float* __restrict__ w2, const float* __restrict__ w3,
          u16* __restrict__ Xf, u16* __restrict__ WS,
          u16* __restrict__ WOh, u16* __restrict__ WOl,
          u32* __restrict__ mws)
{
    const int bid = blockIdx.x;
    const int t = threadIdx.x;

    if (bid < 2048) {                       // ---- X fp32 -> fp16 ----
        size_t i = ((size_t)bid * TPB + t) * 8;
        float4 a = *reinterpret_cast<const float4*>(x + i);
        float4 b = *reinterpret_cast<const float4*>(x + i + 4);
        float v[8] = {a.x, a.y, a.z, a.w, b.x, b.y, b.z, b.w};
        u16x8 hv;
        #pragma unroll
        for (int k = 0; k < 8; ++k) hv[k] = f2h(v[k]);
        *reinterpret_cast<u16x8*>(Xf + i) = hv;
    } else if (bid < 2560) {                // ---- weights ----
        int bb = bid - 2048;
        int y = bb >> 7, xb = bb & 127;
        const float* src = (y == 0) ? w0 : (y == 1) ? w1 : (y == 2) ? w2 : w3;
        float sc = (y == 0) ? QSCALE : 1.0f;
        size_t i = ((size_t)xb * TPB + t) * 8;
        float4 a = *reinterpret_cast<const float4*>(src + i);
        float4 b = *reinterpret_cast<const float4*>(src + i + 4);
        float v[8] = {a.x, a.y, a.z, a.w, b.x, b.y, b.z, b.w};
        if (y < 3) {
            size_t base = (size_t)y * 262144;
            u16x8 hv;
            #pragma unroll
            for (int k = 0; k < 8; ++k) hv[k] = f2h(v[k] * sc);
            *reinterpret_cast<u16x8*>(WS + base + i) = hv;
        } else {
            u16x8 hv, lv;
            #pragma unroll
            for (int k = 0; k < 8; ++k) {
                _Float16 h = (_Float16)v[k];
                hv[k] = __builtin_bit_cast(u16, h);
                lv[k] = f2h(v[k] - (float)h);
            }
            *reinterpret_cast<u16x8*>(WOh + i) = hv;
            *reinterpret_cast<u16x8*>(WOl + i) = lv;
        }
    } else {                                // ---- compact bf16 mask table ----
        int mb = bid - 2560;                // 0..80
        int mq9 = mb / 9, mk9 = mb % 9;
        int w = t >> 6, l = t & 63, lh = l >> 5, l31 = l & 31;
        int q = mq9 * 16 + (w & 1) * 32 + l31;
        int qx = q % 12, qy = (q / 12) % 12;
        u32 words[8];
        #pragma unroll
        for (int jr = 0; jr < 8; ++jr) {
            u16 wb[2];
            #pragma unroll
            for (int e = 0; e < 2; ++e) {
                int r = jr * 2 + e;
                int key = mk9 * 16 + (w >> 1) * 32 + (r & 3) + 8 * (r >> 2) + 4 * lh;
                int kx = key % 12, ky = (key / 12) % 12;
                int dx = qx - kx; dx = dx < 0 ? -dx : dx; dx = dx < 12 - dx ? dx : 12 - dx;
                int dy = qy - ky; dy = dy < 0 ? -dy : dy; dy = dy < 12 - dy ? dy : 12 - dy;
                int d = dx + dy;
                float wgt = (d <= 2) ? 1.0f : __expf(-(float)d);
                wb[e] = f2bf(wgt);
            }
            words[jr] = (u32)wb[0] | ((u32)wb[1] << 16);
        }
        u32* dst = &mws[(size_t)((mb * 4 + w) * 64 + l) * 8];
        #pragma unroll
        for (int jr = 0; jr < 8; ++jr) dst[jr] = words[jr];
    }
}

// ---------------------------------------------------------------------------
// Single-precision fp16 QKV GEMM, XCD-remapped, BK=32, 128x128 tile, 2-phase
// double buffer (round-19 proven best: 109.2 us total).
// ---------------------------------------------------------------------------
__global__ __launch_bounds__(TPB)
void gemm_qkv(const u16* __restrict__ Xf, const u16* __restrict__ Wc,
              const float* __restrict__ bq, const float* __restrict__ bk,
              const float* __restrict__ bv,
              u16* __restrict__ Qf, u16* __restrict__ Kf, u16* __restrict__ Vt)
{
    __shared__ __align__(16) u16 XS[2][128][32];
    __shared__ __align__(16) u16 WSs[2][128][32];

    const int bid = blockIdx.x;            // 768 blocks
    const int xcd = bid & 7, idx = bid >> 3;   // idx 0..95
    const int m0 = (xcd * 8 + (idx & 7)) * 128;
    const int n0 = (idx >> 3) * 128;           // 0..11 n-tiles

    const int t  = threadIdx.x;
    const int wv = t >> 6, l = t & 63, lr = l & 15, lg = l >> 4;
    const int wm = (wv >> 1) * 64, wn = (wv & 1) * 64;

    const u16* gsrc = (wv < 2) ? Xf : Wc;
    const int rbase = (wv < 2) ? m0 : n0;
    const int rgrp  = (wv & 1) * 64;
    const int srow  = l >> 2;
    const int scol  = ((l & 3) ^ ((l >> 3) & 3)) * 8;   // inverse-swizzled source
    const int swc   = (lg ^ ((lr >> 1) & 3)) * 8;       // swizzled read col

    f32x4 acc[4][4];
    #pragma unroll
    for (int i = 0; i < 4; ++i)
        #pragma unroll
        for (int j = 0; j < 4; ++j) acc[i][j] = f32x4{};

    #define QSTAGE(BUF, K0)                                                        \
        {   _Pragma("unroll")                                                      \
            for (int j_ = 0; j_ < 4; ++j_) {                                       \
                int row0 = rgrp + j_ * 16;                                         \
                const u16* g = gsrc + (size_t)(rbase + row0 + srow) * 512 + (K0) + scol; \
                if (wv < 2)                                                        \
                    __builtin_amdgcn_global_load_lds(                              \
                        (const __attribute__((address_space(1))) void*)g,          \
                        (__attribute__((address_space(3))) void*)&XS[BUF][row0][0],\
                        16, 0, 0);                                                 \
                else                                                               \
                    __builtin_amdgcn_global_load_lds(                              \
                        (const __attribute__((address_space(1))) void*)g,          \
                        (__attribute__((address_space(3))) void*)&WSs[BUF][row0][0],\
                        16, 0, 0);                                                 \
            } }

    QSTAGE(0, 0);
    __syncthreads();

    for (int kk = 0; kk < 16; ++kk) {
        const int cur = kk & 1;
        if (kk < 15) QSTAGE(cur ^ 1, (kk + 1) * 32);   // prefetch under compute

        f16x8 af[4], bfr[4];
        #pragma unroll
        for (int mi = 0; mi < 4; ++mi)
            af[mi] = *reinterpret_cast<const f16x8*>(&XS[cur][wm + mi*16 + lr][swc]);
        #pragma unroll
        for (int ni = 0; ni < 4; ++ni)
            bfr[ni] = *reinterpret_cast<const f16x8*>(&WSs[cur][wn + ni*16 + lr][swc]);
        #pragma unroll
        for (int mi = 0; mi < 4; ++mi)
            #pragma unroll
            for (int ni = 0; ni < 4; ++ni)
                acc[mi][ni] = MFMA16F(af[mi], bfr[ni], acc[mi][ni]);

        __syncthreads();   // drains prefetch (ready for kk+1); orders buffer reuse
    }

    const int proj = n0 >> 9;
    const float* bias = (proj == 0) ? bq : (proj == 1) ? bk : bv;
    const float bsc = (proj == 0) ? QSCALE : 1.0f;
    #pragma unroll
    for (int ni = 0; ni < 4; ++ni) {
        int gn = n0 + wn + ni*16 + lr;
        int nn = gn & 511;
        float bb = bias[nn] * bsc;
        #pragma unroll
        for (int mi = 0; mi < 4; ++mi) {
            #pragma unroll
            for (int j = 0; j < 4; ++j) {
                int gm = m0 + wm + mi*16 + lg*4 + j;
                float v = acc[mi][ni][j] + bb;
                int b = gm >> 11, tt = gm & 2047, hh = nn >> 6, d = nn & 63;
                if (proj == 0) {
                    Qf[(((size_t)(b*8 + hh) * 2048) + tt) * 64 + d] = f2h(v);
                } else if (proj == 1) {
                    Kf[(((size_t)(b*8 + hh) * 2048) + tt) * 64 + d] = f2h(v);
                } else {
                    int ttp = (tt & ~12) | ((tt & 4) << 1) | ((tt & 8) >> 1);
                    Vt[(((size_t)(b*8 + hh) * 64) + d) * 2048 + ttp] = f2h(v);
                }
            }
        }
    }
}

// ---------------------------------------------------------------------------
// 2-term out-projection GEMM, 64x128 tiles, XCD-remapped (round-17, frozen).
// ---------------------------------------------------------------------------
__global__ __launch_bounds__(TPB)
void gemm_o2(const u16* __restrict__ A_g, const u16* __restrict__ Bh_g,
             const u16* __restrict__ Bl_g,
             const float* __restrict__ b0, float* __restrict__ outf)
{
    __shared__ __align__(16) u16 AS[64][32];
    __shared__ __align__(16) u16 BhS[128][32];
    __shared__ __align__(16) u16 BlS[128][32];

    const int bid = blockIdx.x;            // 512 blocks
    const int xcd = bid & 7, idx = bid >> 3;   // idx 0..63
    const int m0 = (xcd * 16 + (idx & 15)) * 64;
    const int n0 = (idx >> 4) * 128;           // 0..3

    const int t  = threadIdx.x;
    const int wv = t >> 6, l = t & 63, lr = l & 15, lg = l >> 4;
    const int wm = (wv >> 1) * 32, wn = (wv & 1) * 64;

    const u16* gsrc = (wv < 2) ? A_g : (wv == 2) ? Bh_g : Bl_g;
    const int rbase = (wv < 2) ? m0 : n0;
    const int rgoff = (wv == 1) ? 32 : 0;
    const int nld   = (wv < 2) ? 2 : 8;
    u16 (*dst)[32] = (wv < 2) ? AS : (wv == 2) ? BhS : BlS;
    const int srow  = l >> 2;
    const int scol  = ((l & 3) ^ ((l >> 3) & 3)) * 8;
    const int swc   = (lg ^ ((lr >> 1) & 3)) * 8;

    f32x4 acc[2][4];
    #pragma unroll
    for (int i = 0; i < 2; ++i)
        #pragma unroll
        for (int j = 0; j < 4; ++j) acc[i][j] = f32x4{};

    for (int k0 = 0; k0 < 512; k0 += 32) {
        __syncthreads();
        for (int j = 0; j < nld; ++j) {
            int row0 = rgoff + j * 16;
            const u16* g = gsrc + (size_t)(rbase + row0 + srow) * 512 + k0 + scol;
            __builtin_amdgcn_global_load_lds(
                (const __attribute__((address_space(1))) void*)g,
                (__attribute__((address_space(3))) void*)&dst[row0][0],
                16, 0, 0);
        }
        __syncthreads();

        f16x8 af[2], bfh[4], bfl[4];
        #pragma unroll
        for (int mi = 0; mi < 2; ++mi)
            af[mi] = *reinterpret_cast<const f16x8*>(&AS[wm + mi*16 + lr][swc]);
        #pragma unroll
        for (int ni = 0; ni < 4; ++ni) {
            bfh[ni] = *reinterpret_cast<const f16x8*>(&BhS[wn + ni*16 + lr][swc]);
            bfl[ni] = *reinterpret_cast<const f16x8*>(&BlS[wn + ni*16 + lr][swc]);
        }
        #pragma unroll
        for (int mi = 0; mi < 2; ++mi)
            #pragma unroll
            for (int ni = 0; ni < 4; ++ni) {
                acc[mi][ni] = MFMA16F(af[mi], bfh[ni], acc[mi][ni]);
                acc[mi][ni] = MFMA16F(af[mi], bfl[ni], acc[mi][ni]);
            }
    }

    #pragma unroll
    for (int ni = 0; ni < 4; ++ni) {
        int gn = n0 + wn + ni*16 + lr;
        float bb = b0[gn];
        #pragma unroll
        for (int mi = 0; mi < 2; ++mi) {
            #pragma unroll
            for (int j = 0; j < 4; ++j) {
                int gm = m0 + wm + mi*16 + lg*4 + j;
                outf[(size_t)gm * 512 + gn] = acc[mi][ni][j] + bb;
            }
        }
    }
}

// ---------------------------------------------------------------------------
// Flash attention: round-17 exact (byte-identical; 53.5 us / 9.77e-4 proven).
// ---------------------------------------------------------------------------
__device__ __forceinline__ int lidx(int row, int col) {    // col multiple of 8
    return row * 64 + (col ^ ((row & 7) << 3));
}

__global__ __launch_bounds__(ATPB)
void attn32(const u16* __restrict__ Qf_g, const u16* __restrict__ K_g,
            const u16* __restrict__ Vt_g, const u32* __restrict__ mws,
            u16* __restrict__ AO)
{
    __shared__ __align__(16) u16 SMEM[16384];   // KS dbuf | VS dbuf; reused as OSC
    __shared__ float SC[8][64];
    __shared__ float ILS[128];
    u16* KS0 = SMEM;            // [2][4096]
    u16* VS0 = SMEM + 8192;     // [2][4096]

    const int t = threadIdx.x;
    int id  = blockIdx.x;                 // 512 blocks: 8 XCD x 4 bh x 16 q-tiles
    int xcd = id & 7, seq = id >> 3;
    int bh  = xcd * 4 + (seq >> 4);
    int qt  = seq & 15;
    const int q0 = qt * 128;
    const int b = bh >> 3, h = bh & 7;
    const int w = t >> 6, l = t & 63, lh = l >> 5, l31 = l & 31;
    const int qg = w >> 1, kh = w & 1;
    const int mq9 = ((q0 + qg * 32) % 144) >> 4;

    // Q B-fragments (single fp16): col q = q0 + qg*32 + l31, k = ks*16 + lh*8 + j
    const u16* Qfb = Qf_g + ((size_t)bh * 2048 + q0 + qg * 32 + l31) * 64;
    f16x8 qf[4];
    #pragma unroll
    for (int ks = 0; ks < 4; ++ks)
        qf[ks] = *reinterpret_cast<const f16x8*>(&Qfb[ks * 16 + lh * 8]);

    const u16* Kb = K_g  + (size_t)bh * 2048 * 64;
    const u16* Vb = Vt_g + (size_t)bh * 64 * 2048;
    const int sr = t >> 3, sc8 = (t & 7) * 8;

    // prologue: tile0 -> buf0, prefetch tile1 into regs
    u16x8 kst = *reinterpret_cast<const u16x8*>(&Kb[(size_t)sr * 64 + sc8]);
    u16x8 vst = *reinterpret_cast<const u16x8*>(&Vb[(size_t)sr * 2048 + sc8]);
    *reinterpret_cast<u16x8*>(&KS0[lidx(sr, sc8)]) = kst;
    *reinterpret_cast<u16x8*>(&VS0[lidx(sr, sc8)]) = vst;
    kst = *reinterpret_cast<const u16x8*>(&Kb[(size_t)(64 + sr) * 64 + sc8]);
    vst = *reinterpret_cast<const u16x8*>(&Vb[(size_t)sr * 2048 + 64 + sc8]);
    __syncthreads();

    f32x16 o0 = {}, o1 = {};
    float lrow = 0.f;

    for (int kt = 0; kt < 32; ++kt) {
        const int cur = kt & 1;

        // bf16-packed mask words (L2-resident; consumed after QK^T)
        int mk9 = (4 * kt) % 9;
        const u32* mp = &mws[(size_t)((((mq9 * 9 + mk9) * 4 + (kh << 1)) * 64 + l)) * 8];
        u32x4 mwa = *reinterpret_cast<const u32x4*>(mp);
        u32x4 mwb = *reinterpret_cast<const u32x4*>(mp + 4);

        // S^T = K Q^T (single chain, 4 MFMA32)
        f32x16 st = {};
        __builtin_amdgcn_s_setprio(1);
        #pragma unroll
        for (int ks = 0; ks < 4; ++ks) {
            f16x8 kf = *reinterpret_cast<const f16x8*>(&KS0[cur * 4096 + lidx(kh * 32 + l31, ks * 16 + lh * 8)]);
            st = MFMA32F(kf, qf[ks], st);
        }
        __builtin_amdgcn_s_setprio(0);

        // stage next tile into the other buffer; prefetch tile kt+2
        if (kt < 31) {
            *reinterpret_cast<u16x8*>(&KS0[(cur ^ 1) * 4096 + lidx(sr, sc8)]) = kst;
            *reinterpret_cast<u16x8*>(&VS0[(cur ^ 1) * 4096 + lidx(sr, sc8)]) = vst;
        }
        if (kt < 30) {
            int k0n = (kt + 2) * 64;
            kst = *reinterpret_cast<const u16x8*>(&Kb[(size_t)(k0n + sr) * 64 + sc8]);
            vst = *reinterpret_cast<const u16x8*>(&Vb[(size_t)sr * 2048 + k0n + sc8]);
        }

        // p = exp2(s * w); raw v_exp_f32 (guard-free; args well in range)
        float p[16];
        #pragma unroll
        for (int r = 0; r < 16; ++r) {
            u32 word = (r < 8) ? mwa[r >> 1] : mwb[(r >> 1) - 4];
            u32 bits = (r & 1) ? (word & 0xFFFF0000u) : (word << 16);
            float wgt = __uint_as_float(bits);
            p[r] = __builtin_amdgcn_exp2f(st[r] * wgt);
            lrow += p[r];
        }

        // PV: quantize P to fp16 (RNE scalar) -> direct A-frag
        __builtin_amdgcn_s_setprio(1);
        #pragma unroll
        for (int ks = 0; ks < 2; ++ks) {
            const int base = ks * 8;
            f16x8 pa;
            #pragma unroll
            for (int j = 0; j < 8; ++j) pa[j] = (_Float16)p[base + j];
            f16x8 v0 = *reinterpret_cast<const f16x8*>(&VS0[cur * 4096 + lidx(l31,      kh * 32 + ks * 16 + lh * 8)]);
            f16x8 v1 = *reinterpret_cast<const f16x8*>(&VS0[cur * 4096 + lidx(32 + l31, kh * 32 + ks * 16 + lh * 8)]);
            o0 = MFMA32F(pa, v0, o0);
            o1 = MFMA32F(pa, v1, o1);
        }
        __builtin_amdgcn_s_setprio(0);
        __syncthreads();
    }

    // ---- merge: lrow across (lane-half, key-half); O across key-halves ----
    SC[w][l] = lrow;
    __syncthreads();
    float* OSC = (float*)SMEM;                    // [128 q][64 d] = 32 KB
    if (kh == 1) {
        #pragma unroll
        for (int r = 0; r < 16; ++r) {
            int q = qg * 32 + (r & 3) + 8 * (r >> 2) + 4 * lh;
            OSC[q * 64 + l31]      = o0[r];
            OSC[q * 64 + 32 + l31] = o1[r];
        }
    } else if (l < 32) {
        float s = SC[qg*2][l31] + SC[qg*2][l31 + 32] + SC[qg*2 + 1][l31] + SC[qg*2 + 1][l31 + 32];
        ILS[qg * 32 + l31] = 1.0f / s;
    }
    __syncthreads();
    if (kh == 0) {
        #pragma unroll
        for (int r = 0; r < 16; ++r) {
            int q = qg * 32 + (r & 3) + 8 * (r >> 2) + 4 * lh;
            float il = ILS[q];
            float v0 = (o0[r] + OSC[q * 64 + l31]) * il;
            float v1 = (o1[r] + OSC[q * 64 + 32 + l31]) * il;
            size_t row = (size_t)b * 2048 + q0 + q;
            size_t off0 = row * 512 + h * 64 + l31;
            AO[off0]      = f2h(v0);
            AO[off0 + 32] = f2h(v1);
        }
    }
}

// ---------------------------------------------------------------------------
extern "C" void kernel_launch(void* const* d_in, const int* in_sizes, int n_in,
                              void* d_out, int out_size, void* d_ws, size_t ws_size,
                              hipStream_t stream)
{
    (void)in_sizes; (void)n_in; (void)out_size; (void)ws_size;
    const float* x  = (const float*)d_in[0];
    const float* Wq = (const float*)d_in[1];
    const float* bq = (const float*)d_in[2];
    const float* Wk = (const float*)d_in[3];
    const float* bk = (const float*)d_in[4];
    const float* Wv = (const float*)d_in[5];
    const float* bv = (const float*)d_in[6];
    const float* Wo = (const float*)d_in[7];
    const float* bo = (const float*)d_in[8];
    float* out = (float*)d_out;

    // workspace (~35 MB):
    u16* Xf  = (u16*)d_ws;                // 8 MB (reused as AO after QKV)
    u16* WS  = Xf + 4194304;              // 1.5 MB ([1536][512] f16, Wq*QSCALE)
    u16* WOh = WS + 786432;               // 0.5 MB
    u16* WOl = WOh + 262144;              // 0.5 MB
    u16* Qf  = WOl + 262144;              // 8 MB
    u16* Kf  = Qf + 4194304;              // 8 MB
    u16* Vt  = Kf + 4194304;              // 8 MB (key-permuted transposed)
    u32* MW  = (u32*)(Vt + 4194304);      // 648 KB (bf16-packed compact mask)
    u16* AO  = Xf;

    // fused prep: X cvt (2048) + weights (512) + mask table (81)
    prep<<<2641, TPB, 0, stream>>>(x, Wq, Wk, Wv, Wo, Xf, WS, WOh, WOl, MW);

    // fused QKV projection: 768 blocks, XCD-remapped, BK=32 + 2-phase dbuf
    gemm_qkv<<<768, TPB, 0, stream>>>(Xf, WS, bq, bk, bv, Qf, Kf, Vt);

    // 8-wave attention: 512 blocks x 512 threads
    attn32<<<512, ATPB, 0, stream>>>(Qf, Kf, Vt, MW, AO);

    // output projection (2-term), 64x128 tiles, XCD-remapped
    gemm_o2<<<512, TPB, 0, stream>>>(AO, WOh, WOl, bo, out);
}